// Round 4
// baseline (1151.919 us; speedup 1.0000x reference)
//
#include <hip/hip_runtime.h>

// RecursiveLSTM: B=1024, T=96, H=50, num_pred=12. One block per batch elem,
// 1152 serial LSTM steps in-kernel. Gate g = wave*50 + lane (lanes 0-49):
// all 4 waves/SIMDs carry identical load. W_hh row (50 floats) held in VGPRs,
// PINNED via empty asm ties -- rounds 1-3 showed the backend otherwise sinks
// the (rematerializable) const loads into the t-loop (VGPR_Count 36/52,
// ~212 instr/step/wave instead of ~75).

#define HSZ   50
#define TLEN  96
#define MAXP  16       // >= num_pred

__device__ __forceinline__ float tanh_(float x) {
    // 1 - 2/(exp(2x)+1): no inf/inf NaN at large |x|
    return 1.0f - 2.0f / (__expf(2.0f * x) + 1.0f);
}

// Make a loaded value asm-defined: not rematerializable, cannot be sunk.
#define PIN4(v) asm volatile("" : "+v"(v.x), "+v"(v.y), "+v"(v.z), "+v"(v.w))

__global__ __launch_bounds__(256)
__attribute__((amdgpu_waves_per_eu(4, 4)))   // 128-VGPR budget; grid is 4 blocks/CU anyway
void rec_lstm_kernel(const float* __restrict__ x,
                     const float* __restrict__ W_ih,
                     const float* __restrict__ W_hh,
                     const float* __restrict__ b_ih,
                     const float* __restrict__ b_hh,
                     const float* __restrict__ W_fc,
                     const float* __restrict__ b_fc,
                     const int*   __restrict__ num_pred,
                     float*       __restrict__ out)
{
    const int  b    = blockIdx.x;
    const int  tid  = threadIdx.x;
    const int  wave = tid >> 6;
    const int  lane = tid & 63;
    const bool act  = (lane < HSZ);
    const int  g    = wave * HSZ + (act ? lane : HSZ - 1);   // gate owned (clamped)

    __shared__ float xp[TLEN + MAXP];            // input window ++ predictions
    __shared__ __align__(16) float hbuf[4][52];  // per-wave h copy (13 float4)
    __shared__ float gates[2][4 * HSZ];          // double-buffered (1 barrier/step)

    // ---- one-time preload: W_hh row for gate g into 50 pinned VGPRs ----
    const float* wr = W_hh + g * HSZ;
    float4 w0, w1, w2, w3, w4, w5, w6, w7, w8, w9, w10, w11;
#define LDW(i) w##i = make_float4(wr[4*(i)], wr[4*(i)+1], wr[4*(i)+2], wr[4*(i)+3])
    LDW(0); LDW(1); LDW(2); LDW(3); LDW(4); LDW(5);
    LDW(6); LDW(7); LDW(8); LDW(9); LDW(10); LDW(11);
#undef LDW
    float wc0 = wr[48], wc1 = wr[49];
    float wih  = W_ih[g];
    float bsum = b_ih[g] + b_hh[g];
    PIN4(w0); PIN4(w1); PIN4(w2);  PIN4(w3);  PIN4(w4);  PIN4(w5);
    PIN4(w6); PIN4(w7); PIN4(w8);  PIN4(w9);  PIN4(w10); PIN4(w11);
    asm volatile("" : "+v"(wc0), "+v"(wc1), "+v"(wih), "+v"(bsum));

    const float wfc = W_fc[act ? lane : 0];
    if (tid < TLEN) xp[tid] = x[b * TLEN + tid];
    const float bfc = b_fc[0];
    const int   NP  = num_pred[0];

    // fused nonlinearity: a = m*sigmoid(m*acc) + (1-m); wave 2 owns gates g(100-149) -> tanh
    const float m_   = (wave == 2) ? 2.0f : 1.0f;
    const float add_ = 1.0f - m_;

    float c   = 0.f;     // per-wave-redundant cell state (lanes < 50)
    int   par = 0;

    __syncthreads();     // xp visible

    for (int p = 0; p < NP; ++p) {
        if (lane < 52) hbuf[wave][lane] = 0.f;   // wave-private: no barrier needed
        c = 0.f;

        for (int t = 0; t < TLEN; ++t) {
            const float xv = xp[p + t];          // uniform-address broadcast read

            const float4* hb4 = (const float4*)&hbuf[wave][0];  // broadcast reads
            float a0 = fmaf(wih, xv, bsum), a1 = 0.f, a2 = 0.f, a3 = 0.f;
#define ACCL(i) { float4 hv = hb4[i]; \
                  a0 = fmaf(w##i.x, hv.x, a0); a1 = fmaf(w##i.y, hv.y, a1); \
                  a2 = fmaf(w##i.z, hv.z, a2); a3 = fmaf(w##i.w, hv.w, a3); }
            ACCL(0) ACCL(1) ACCL(2) ACCL(3) ACCL(4)  ACCL(5)
            ACCL(6) ACCL(7) ACCL(8) ACCL(9) ACCL(10) ACCL(11)
#undef ACCL
            {   float2 hv = *(const float2*)&hbuf[wave][48];
                a0 = fmaf(wc0, hv.x, a0); a1 = fmaf(wc1, hv.y, a1); }
            const float acc = (a0 + a1) + (a2 + a3);

            const float sig = 1.0f / (1.0f + __expf(-m_ * acc));
            if (act) gates[par][g] = fmaf(m_, sig, add_);
            __syncthreads();   // gates from all waves visible

            if (act) {         // redundant per-wave h/c update (identical fp ops)
                const float gi = gates[par][lane];
                const float gf = gates[par][lane + HSZ];
                const float gg = gates[par][lane + 2 * HSZ];
                const float go = gates[par][lane + 3 * HSZ];
                c = fmaf(gf, c, gi * gg);
                hbuf[wave][lane] = go * tanh_(c);
            }
            par ^= 1;          // next step uses the other gate buffer
        }

        // ---- FC head: wave 0 reduces its h copy ----
        if (wave == 0) {
            float v = act ? hbuf[0][lane] * wfc : 0.f;
            #pragma unroll
            for (int off = 32; off >= 1; off >>= 1)
                v += __shfl_down(v, off, 64);
            if (lane == 0) {
                const float pr = v + bfc;
                xp[TLEN + p] = pr;               // feed back as next input
                out[b * NP + p] = pr;
            }
        }
        __syncthreads();       // xp[TLEN+p] visible before next pass
    }
}

extern "C" void kernel_launch(void* const* d_in, const int* in_sizes, int n_in,
                              void* d_out, int out_size, void* d_ws, size_t ws_size,
                              hipStream_t stream)
{
    const float* x    = (const float*)d_in[0];
    const float* W_ih = (const float*)d_in[1];
    const float* W_hh = (const float*)d_in[2];
    const float* b_ih = (const float*)d_in[3];
    const float* b_hh = (const float*)d_in[4];
    const float* W_fc = (const float*)d_in[5];
    const float* b_fc = (const float*)d_in[6];
    const int*   np   = (const int*)d_in[7];
    float* out = (float*)d_out;

    const int B = in_sizes[0] / TLEN;   // 1024
    rec_lstm_kernel<<<B, 256, 0, stream>>>(x, W_ih, W_hh, b_ih, b_hh,
                                           W_fc, b_fc, np, out);
}